// Round 8
// baseline (52.588 us; speedup 1.0000x reference)
//
#include <hip/hip_runtime.h>

// Table-batched embedding bags: weights [T*E, D=64] f32, indices [N] local,
// offsets [T*B+1] ragged bags (segment s = t*B + b), out [B, T, D] f32.
//
// R4 structure (one wave/bag; lane=(r,c); two 32-row halves per 64-row
// iteration; 8 gathers of v[8] live per half -> low VGPR, high occupancy).
// Only change vs R4: index delivery. Each slot's 16 lanes load the slot's 8
// indices as two ALIGNED int4 broadcast loads (uniform addr within the slot
// -> one line lookup, no DS ops / lgkmcnt stage). Alignment from starting at
// start&~7; rows outside [start,end) are exec-masked from gather+accumulate
// (their index values belong to neighboring bags, addresses stay in-bounds).

__global__ __launch_bounds__(256) void emb_bags_kernel(
    const float* __restrict__ weights,
    const int*   __restrict__ table_offsets,
    const int*   __restrict__ indices,
    const int*   __restrict__ offsets,
    float*       __restrict__ out,
    int N, int TB, int B, int T)
{
    const int wave = (blockIdx.x * blockDim.x + threadIdx.x) >> 6;
    if (wave >= TB) return;
    const int lane = threadIdx.x & 63;
    const int c = lane & 15;   // float4 chunk within row
    const int r = lane >> 4;   // row slot 0..3

    const int t = wave / B;
    const int b = wave - t * B;
    const int start = offsets[wave];
    const int end   = offsets[wave + 1];
    const long long tbase = table_offsets[t];

    const float4* __restrict__ w4 = (const float4*)weights;

    float4 a0 = make_float4(0.f, 0.f, 0.f, 0.f);
    float4 a1 = a0;

    const int astart = start & ~7;       // 32B-aligned index base

    for (int i = astart; i < end; i += 64) {
        #pragma unroll
        for (int h = 0; h < 2; ++h) {
            const int base = i + (h << 5) + (r << 3);   // slot's 8 rows, aligned

            int id[8];
            if (base + 8 <= N) {          // two aligned int4 broadcast loads
                const int4 q0 = *(const int4*)(indices + base);
                const int4 q1 = *(const int4*)(indices + base + 4);
                id[0] = q0.x; id[1] = q0.y; id[2] = q0.z; id[3] = q0.w;
                id[4] = q1.x; id[5] = q1.y; id[6] = q1.z; id[7] = q1.w;
            } else {                      // rare tail at the very end of N
                #pragma unroll
                for (int k = 0; k < 8; ++k) {
                    const int p = base + k;
                    id[k] = indices[p < N ? p : (N - 1)];
                }
            }

            // 8 independent gathers, exec-masked to this bag's rows
            float4 v[8];
            #pragma unroll
            for (int k = 0; k < 8; ++k) {
                const int p = base + k;
                v[k] = make_float4(0.f, 0.f, 0.f, 0.f);
                if (p >= start && p < end)
                    v[k] = w4[((size_t)(tbase + id[k]) << 4) + c];
            }

            #pragma unroll
            for (int k = 0; k < 8; k += 2) {
                a0.x += v[k].x;     a0.y += v[k].y;
                a0.z += v[k].z;     a0.w += v[k].w;
                a1.x += v[k + 1].x; a1.y += v[k + 1].y;
                a1.z += v[k + 1].z; a1.w += v[k + 1].w;
            }
        }
    }

    float4 a;
    a.x = a0.x + a1.x;
    a.y = a0.y + a1.y;
    a.z = a0.z + a1.z;
    a.w = a0.w + a1.w;

    // reduce across the 4 row-slots (lane bits 4 and 5)
    #pragma unroll
    for (int m = 16; m < 64; m <<= 1) {
        a.x += __shfl_xor(a.x, m, 64);
        a.y += __shfl_xor(a.y, m, 64);
        a.z += __shfl_xor(a.z, m, 64);
        a.w += __shfl_xor(a.w, m, 64);
    }

    if (r == 0) {
        float4* o4 = (float4*)out;
        o4[(((size_t)b * T + t) << 4) + c] = a;  // out[b, t, c*4 .. c*4+3]
    }
}

extern "C" void kernel_launch(void* const* d_in, const int* in_sizes, int n_in,
                              void* d_out, int out_size, void* d_ws, size_t ws_size,
                              hipStream_t stream) {
    const float* weights       = (const float*)d_in[0];
    const int*   table_offsets = (const int*)d_in[1];
    const int*   indices       = (const int*)d_in[2];
    const int*   offsets       = (const int*)d_in[3];
    float*       out           = (float*)d_out;

    const int T  = in_sizes[1];          // 8
    const int TB = in_sizes[3] - 1;      // T*B
    const int B  = TB / T;               // 2048
    const int N  = in_sizes[2];          // total index rows

    const int threads = 256;             // 4 waves/block
    const int blocks  = (TB * 64 + threads - 1) / threads;
    emb_bags_kernel<<<blocks, threads, 0, stream>>>(
        weights, table_offsets, indices, offsets, out, N, TB, B, T);
}

// Round 9
// 38.219 us; speedup vs baseline: 1.3760x; 1.3760x over previous
//
#include <hip/hip_runtime.h>

// Table-batched embedding bags: weights [T*E, D=64] f32, indices [N] local,
// offsets [T*B+1] ragged bags (segment s = t*B + b), out [B, T, D] f32.
//
// Best-known structure (R4, 38.4 us): one wave per bag. Lane=(r,c):
// r=lane>>4 row-slot, c=lane&15 float4 chunk. Indices loaded ONCE per 64
// rows with a single coalesced VMEM inst (indices[i+lane]) and distributed
// via __shfl (ds_bpermute -> lgkmcnt queue, independent of the gather vmcnt
// queue; exactly one vmcnt-drain point per 64 rows). Gathers: 8 independent
// dwordx4 per lane per 32-row half (128 B/lane in flight) -- measured sweet
// spot: 16 live gathers (R6) costs VGPR/occupancy and regresses; index loads
// in the VMEM queue (R2/R7) create in-order vmcnt serialization and regress.

__global__ __launch_bounds__(256) void emb_bags_kernel(
    const float* __restrict__ weights,
    const int*   __restrict__ table_offsets,
    const int*   __restrict__ indices,
    const int*   __restrict__ offsets,
    float*       __restrict__ out,
    int TB, int B, int T)
{
    const int wave = (blockIdx.x * blockDim.x + threadIdx.x) >> 6;
    if (wave >= TB) return;
    const int lane = threadIdx.x & 63;
    const int c = lane & 15;   // float4 chunk within row
    const int r = lane >> 4;   // row slot 0..3

    const int t = wave / B;
    const int b = wave - t * B;
    const int start = offsets[wave];
    const int end   = offsets[wave + 1];
    const long long tbase = table_offsets[t];

    const float4* __restrict__ w4 = (const float4*)weights;

    float4 a0 = make_float4(0.f, 0.f, 0.f, 0.f);
    float4 a1 = a0;

    for (int i = start; i < end; i += 64) {
        const int e1 = end - 1;
        const int p  = i + lane;
        const int myidx = indices[p <= e1 ? p : e1];   // 1 coalesced VMEM / 64 rows

        #pragma unroll
        for (int h = 0; h < 2; ++h) {                  // two 32-row halves
            const int base = i + (h << 5) + (r << 3);  // this slot's 8 rows
            // distribute indices in-register; then 8 independent gathers
            int id[8];
            #pragma unroll
            for (int k = 0; k < 8; ++k)
                id[k] = __shfl(myidx, (h << 5) + (r << 3) + k, 64);

            float4 v[8];
            #pragma unroll
            for (int k = 0; k < 8; ++k) {
                if (base + k < end)
                    v[k] = w4[((size_t)(tbase + id[k]) << 4) + c];
                else
                    v[k] = make_float4(0.f, 0.f, 0.f, 0.f);
            }

            #pragma unroll
            for (int k = 0; k < 8; k += 2) {
                a0.x += v[k].x;     a0.y += v[k].y;
                a0.z += v[k].z;     a0.w += v[k].w;
                a1.x += v[k + 1].x; a1.y += v[k + 1].y;
                a1.z += v[k + 1].z; a1.w += v[k + 1].w;
            }
        }
    }

    float4 a;
    a.x = a0.x + a1.x;
    a.y = a0.y + a1.y;
    a.z = a0.z + a1.z;
    a.w = a0.w + a1.w;

    // reduce across the 4 row-slots (lane bits 4 and 5)
    #pragma unroll
    for (int m = 16; m < 64; m <<= 1) {
        a.x += __shfl_xor(a.x, m, 64);
        a.y += __shfl_xor(a.y, m, 64);
        a.z += __shfl_xor(a.z, m, 64);
        a.w += __shfl_xor(a.w, m, 64);
    }

    if (r == 0) {
        float4* o4 = (float4*)out;
        o4[(((size_t)b * T + t) << 4) + c] = a;  // out[b, t, c*4 .. c*4+3]
    }
}

extern "C" void kernel_launch(void* const* d_in, const int* in_sizes, int n_in,
                              void* d_out, int out_size, void* d_ws, size_t ws_size,
                              hipStream_t stream) {
    const float* weights       = (const float*)d_in[0];
    const int*   table_offsets = (const int*)d_in[1];
    const int*   indices       = (const int*)d_in[2];
    const int*   offsets       = (const int*)d_in[3];
    float*       out           = (float*)d_out;

    const int T  = in_sizes[1];          // 8
    const int TB = in_sizes[3] - 1;      // T*B
    const int B  = TB / T;               // 2048

    const int threads = 256;             // 4 waves/block
    const int blocks  = (TB * 64 + threads - 1) / threads;
    emb_bags_kernel<<<blocks, threads, 0, stream>>>(
        weights, table_offsets, indices, offsets, out, TB, B, T);
}